// Round 1
// 864.401 us; speedup vs baseline: 1.1722x; 1.1722x over previous
//
#include <hip/hip_runtime.h>
#include <hip/hip_fp16.h>

// MetaPath2Vec loss, round 4: fp8 e4m3 table staged in workspace.
//   R3 (fp16 table, 256MB) loss kernel = 317us at 6.8 TB/s COMBINED L3+HBM
//   service (2.15GB logical gathers); table == L3 size -> ~50% L3 hit,
//   1.05GB HBM fetch. Neither pipe saturated alone; working set is the lever.
//   Fix: fp8 e4m3 table = 128MB (half of L3) -> ~100% L3-resident, logical
//   gather bytes halve to 1.08GB. HW converts: v_cvt_pk_fp8_f32 (encode),
//   v_cvt_pk_f32_fp8 (decode). Epilogue (exp/rcp/log) parallelized across
//   the 8 lanes of a group (one dot's epilogue per lane, not 8x redundant)
//   to absorb the extra decode VALU work.
//   Expected loss err ~0.007 abs (bias = 0.5*E[s(1-s)]*sigma_p^2,
//   sigma_p ~ 0.43) vs tolerance 0.2 that admitted fp16 (err ~5e-3).

constexpr int DIM = 128;
constexpr int CTX = 7;

#if __has_builtin(__builtin_amdgcn_cvt_pk_fp8_f32) && __has_builtin(__builtin_amdgcn_cvt_pk_f32_fp8)
#define FP8_VIA_BUILTIN 1
#else
#define FP8_VIA_BUILTIN 0
#include <hip/hip_fp8.h>
#endif

typedef float f32x2 __attribute__((ext_vector_type(2)));

template<int IMM>
__device__ __forceinline__ int swz_i(int x) {
    return __builtin_amdgcn_ds_swizzle(x, IMM);
}
template<int IMM>
__device__ __forceinline__ float swz_f(float x) {
    return __int_as_float(__builtin_amdgcn_ds_swizzle(__float_as_int(x), IMM));
}
__device__ __forceinline__ float red8(float p) {
    p += swz_f<0x041F>(p);
    p += swz_f<0x081F>(p);
    p += swz_f<0x101F>(p);
    return p;
}

// ---------- fp8 e4m3 (OCP) encode / decode ----------
template<bool HI>
__device__ __forceinline__ unsigned enc2(float x, float y, unsigned old) {
#if FP8_VIA_BUILTIN
    return (unsigned)__builtin_amdgcn_cvt_pk_fp8_f32(x, y, (int)old, HI);
#else
    __hip_fp8_e4m3 a(x), b(y);
    unsigned w = (unsigned)a.__x | ((unsigned)b.__x << 8);
    return HI ? ((old & 0x0000ffffu) | (w << 16))
              : ((old & 0xffff0000u) | w);
#endif
}

template<bool HI>
__device__ __forceinline__ f32x2 dec2(unsigned w) {
#if FP8_VIA_BUILTIN
    return __builtin_amdgcn_cvt_pk_f32_fp8(w, HI);
#else
    unsigned lo = HI ? (w >> 16) : (w & 0xffffu);
    __hip_fp8_e4m3 a, b;
    a.__x = (unsigned char)(lo & 0xff);
    b.__x = (unsigned char)(lo >> 8);
    f32x2 r; r[0] = (float)a; r[1] = (float)b;
    return r;
#endif
}

__device__ __forceinline__ void dec16(uint4 v, float* o) {
    f32x2 t;
    t = dec2<false>(v.x); o[0]  = t[0]; o[1]  = t[1];
    t = dec2<true >(v.x); o[2]  = t[0]; o[3]  = t[1];
    t = dec2<false>(v.y); o[4]  = t[0]; o[5]  = t[1];
    t = dec2<true >(v.y); o[6]  = t[0]; o[7]  = t[1];
    t = dec2<false>(v.z); o[8]  = t[0]; o[9]  = t[1];
    t = dec2<true >(v.z); o[10] = t[0]; o[11] = t[1];
    t = dec2<false>(v.w); o[12] = t[0]; o[13] = t[1];
    t = dec2<true >(v.w); o[14] = t[0]; o[15] = t[1];
}

__device__ __forceinline__ float dot16_fp8(const float* h, uint4 v, float p) {
    f32x2 t;
    t = dec2<false>(v.x); p = fmaf(h[0],  t[0], p); p = fmaf(h[1],  t[1], p);
    t = dec2<true >(v.x); p = fmaf(h[2],  t[0], p); p = fmaf(h[3],  t[1], p);
    t = dec2<false>(v.y); p = fmaf(h[4],  t[0], p); p = fmaf(h[5],  t[1], p);
    t = dec2<true >(v.y); p = fmaf(h[6],  t[0], p); p = fmaf(h[7],  t[1], p);
    t = dec2<false>(v.z); p = fmaf(h[8],  t[0], p); p = fmaf(h[9],  t[1], p);
    t = dec2<true >(v.z); p = fmaf(h[10], t[0], p); p = fmaf(h[11], t[1], p);
    t = dec2<false>(v.w); p = fmaf(h[12], t[0], p); p = fmaf(h[13], t[1], p);
    t = dec2<true >(v.w); p = fmaf(h[14], t[0], p); p = fmaf(h[15], t[1], p);
    return p;
}

__global__ void zero_ws_kernel(double* ws) {
    if (threadIdx.x < 2) ws[threadIdx.x] = 0.0;
}

// f32 -> fp8: read float4 (16B), write packed dword (4 fp8).
__global__ __launch_bounds__(256) void convert_fp8_kernel(
    const float4* __restrict__ in, unsigned* __restrict__ out, int n4)
{
    int i = blockIdx.x * blockDim.x + threadIdx.x;
    const int stride = gridDim.x * blockDim.x;
    for (; i < n4; i += stride) {
        float4 v = in[i];
        unsigned d = enc2<false>(v.x, v.y, 0u);
        d = enc2<true >(v.z, v.w, d);
        out[i] = d;
    }
}

// fp8 gather kernel: 8 lanes per walk-row; row = 128B = 8 uint4.
// Each lane loads ONE uint4 (16 fp8) per referenced row.
// Epilogue: lane sub keeps dot j == sub+1 (red8 broadcasts the sum),
// transcendentals run once per row instead of 6x redundantly.
__global__ __launch_bounds__(256) void mp2v_loss_fp8_kernel(
    const uint4* __restrict__ tab,
    const int*   __restrict__ pos_rw,
    const int*   __restrict__ neg_rw,
    double*      __restrict__ ws,
    int pos_rows, int neg_rows)
{
    const int tid     = blockIdx.x * blockDim.x + threadIdx.x;
    const int sub     = threadIdx.x & 7;
    const int group   = tid >> 3;
    const int ngroups = (gridDim.x * blockDim.x) >> 3;
    const int total   = pos_rows + neg_rows;

    double accPos = 0.0, accNeg = 0.0;

    int row = group;
    int nextIdx = 0;
    if (row < total) {
        const int* rw = (row < pos_rows) ? pos_rw + (size_t)row * CTX
                                         : neg_rw + (size_t)(row - pos_rows) * CTX;
        nextIdx = rw[sub < CTX ? sub : 0];
    }

    for (; row < total; row += ngroups) {
        const bool isPos = row < pos_rows;
        int myidx = nextIdx;
        // prefetch next iteration's indices (breaks idx->load serialization)
        int nrow = row + ngroups;
        if (nrow < total) {
            const int* rw = (nrow < pos_rows) ? pos_rw + (size_t)nrow * CTX
                                              : neg_rw + (size_t)(nrow - pos_rows) * CTX;
            nextIdx = rw[sub < CTX ? sub : 0];
        }

        int idx0 = swz_i<(0<<5)|0x18>(myidx);
        int idx1 = swz_i<(1<<5)|0x18>(myidx);
        int idx2 = swz_i<(2<<5)|0x18>(myidx);
        int idx3 = swz_i<(3<<5)|0x18>(myidx);
        int idx4 = swz_i<(4<<5)|0x18>(myidx);
        int idx5 = swz_i<(5<<5)|0x18>(myidx);
        int idx6 = swz_i<(6<<5)|0x18>(myidx);
        int idx[CTX] = {idx0, idx1, idx2, idx3, idx4, idx5, idx6};

        // h (start row): 8 uint4 per row; lane takes [sub]
        uint4 hv = tab[(size_t)idx[0] * 8 + sub];
        float h[16];
        dec16(hv, h);

        float pmine = 0.0f;
        #pragma unroll
        for (int j = 1; j < CTX; ++j) {
            uint4 cv = tab[(size_t)idx[j] * 8 + sub];
            float p = dot16_fp8(h, cv, 0.0f);
            p = red8(p);               // broadcasts full dot to all 8 lanes
            if (sub == j - 1) pmine = p;
        }

        // one epilogue per row; lanes 0..5 each own one of the 6 dots
        float e = __expf(-fabsf(pmine));
        float r = __frcp_rn(1.0f + e);
        float s = (pmine >= 0.0f ? 1.0f : e) * r;
        float t = isPos ? (s + 1e-15f) : (1.0f - s + 1e-15f);
        float m = (sub < CTX - 1) ? -__logf(t) : 0.0f;
        if (isPos) accPos += (double)m;
        else       accNeg += (double)m;
    }

    #pragma unroll
    for (int off = 32; off > 0; off >>= 1) {
        accPos += __shfl_down(accPos, off, 64);
        accNeg += __shfl_down(accNeg, off, 64);
    }
    __shared__ double sP[4], sN[4];
    const int wave = threadIdx.x >> 6;
    if ((threadIdx.x & 63) == 0) { sP[wave] = accPos; sN[wave] = accNeg; }
    __syncthreads();
    if (threadIdx.x == 0) {
        atomicAdd(&ws[0], sP[0] + sP[1] + sP[2] + sP[3]);
        atomicAdd(&ws[1], sN[0] + sN[1] + sN[2] + sN[3]);
    }
}

// ---------- f32 fallback (round-2 kernel), used when ws too small ----------
__global__ __launch_bounds__(256) void mp2v_loss_f32_kernel(
    const float* __restrict__ emb,
    const int*   __restrict__ pos_rw,
    const int*   __restrict__ neg_rw,
    double*      __restrict__ ws,
    int pos_rows, int neg_rows)
{
    const int tid     = blockIdx.x * blockDim.x + threadIdx.x;
    const int sub     = threadIdx.x & 7;
    const int group   = tid >> 3;
    const int ngroups = (gridDim.x * blockDim.x) >> 3;
    const int total   = pos_rows + neg_rows;

    double accPos = 0.0, accNeg = 0.0;

    for (int row = group; row < total; row += ngroups) {
        const bool isPos = row < pos_rows;
        const int* rw = isPos ? pos_rw + (size_t)row * CTX
                              : neg_rw + (size_t)(row - pos_rows) * CTX;
        int myidx = rw[sub < CTX ? sub : 0];

        int idx0 = swz_i<(0<<5)|0x18>(myidx);
        int idx1 = swz_i<(1<<5)|0x18>(myidx);
        int idx2 = swz_i<(2<<5)|0x18>(myidx);
        int idx3 = swz_i<(3<<5)|0x18>(myidx);
        int idx4 = swz_i<(4<<5)|0x18>(myidx);
        int idx5 = swz_i<(5<<5)|0x18>(myidx);
        int idx6 = swz_i<(6<<5)|0x18>(myidx);
        int idx[CTX] = {idx0, idx1, idx2, idx3, idx4, idx5, idx6};

        const float* h0p = emb + (size_t)idx[0] * DIM + sub * 4;
        float4 ha = *(const float4*)(h0p);
        float4 hb = *(const float4*)(h0p + 32);
        float4 hc = *(const float4*)(h0p + 64);
        float4 hd = *(const float4*)(h0p + 96);

        float rowLoss = 0.0f;
        #pragma unroll
        for (int j = 1; j < CTX; ++j) {
            const float* cp = emb + (size_t)idx[j] * DIM + sub * 4;
            float4 ca = *(const float4*)(cp);
            float4 cb = *(const float4*)(cp + 32);
            float4 cc = *(const float4*)(cp + 64);
            float4 cd = *(const float4*)(cp + 96);
            float p = ha.x*ca.x + ha.y*ca.y + ha.z*ca.z + ha.w*ca.w;
            p = fmaf(hb.x, cb.x, fmaf(hb.y, cb.y, fmaf(hb.z, cb.z, fmaf(hb.w, cb.w, p))));
            p = fmaf(hc.x, cc.x, fmaf(hc.y, cc.y, fmaf(hc.z, cc.z, fmaf(hc.w, cc.w, p))));
            p = fmaf(hd.x, cd.x, fmaf(hd.y, cd.y, fmaf(hd.z, cd.z, fmaf(hd.w, cd.w, p))));
            p = red8(p);

            float e = __expf(-fabsf(p));
            float r = __frcp_rn(1.0f + e);
            float s = (p >= 0.0f ? 1.0f : e) * r;
            float t = isPos ? (s + 1e-15f) : (1.0f - s + 1e-15f);
            rowLoss -= __logf(t);
        }
        float m = (sub == 0) ? rowLoss : 0.0f;
        if (isPos) accPos += (double)m;
        else       accNeg += (double)m;
    }

    #pragma unroll
    for (int off = 32; off > 0; off >>= 1) {
        accPos += __shfl_down(accPos, off, 64);
        accNeg += __shfl_down(accNeg, off, 64);
    }
    __shared__ double sP[4], sN[4];
    const int wave = threadIdx.x >> 6;
    if ((threadIdx.x & 63) == 0) { sP[wave] = accPos; sN[wave] = accNeg; }
    __syncthreads();
    if (threadIdx.x == 0) {
        atomicAdd(&ws[0], sP[0] + sP[1] + sP[2] + sP[3]);
        atomicAdd(&ws[1], sN[0] + sN[1] + sN[2] + sN[3]);
    }
}

__global__ void finalize_kernel(const double* __restrict__ ws,
                                float* __restrict__ out,
                                double invPosCnt, double invNegCnt)
{
    out[0] = (float)(ws[0] * invPosCnt + ws[1] * invNegCnt);
}

extern "C" void kernel_launch(void* const* d_in, const int* in_sizes, int n_in,
                              void* d_out, int out_size, void* d_ws, size_t ws_size,
                              hipStream_t stream)
{
    const float* emb    = (const float*)d_in[0];
    const int*   pos_rw = (const int*)d_in[1];
    const int*   neg_rw = (const int*)d_in[2];
    float*       out    = (float*)d_out;
    double*      ws     = (double*)d_ws;

    const int pos_rows = in_sizes[1] / CTX;   // 200000
    const int neg_rows = in_sizes[2] / CTX;   // 1000000
    const int n_emb_elems = in_sizes[0];      // 128,000,128

    const size_t table_bytes = (size_t)n_emb_elems;       // fp8 table, 1B/elem
    const size_t need = 256 + table_bytes;

    hipLaunchKernelGGL(zero_ws_kernel, dim3(1), dim3(64), 0, stream, ws);

    const int blocks = 4096;
    if (ws_size >= need) {
        unsigned* tab_w = (unsigned*)((char*)d_ws + 256);
        hipLaunchKernelGGL(convert_fp8_kernel, dim3(4096), dim3(256), 0, stream,
                           (const float4*)emb, tab_w, n_emb_elems / 4);
        hipLaunchKernelGGL(mp2v_loss_fp8_kernel, dim3(blocks), dim3(256), 0, stream,
                           (const uint4*)((char*)d_ws + 256), pos_rw, neg_rw, ws,
                           pos_rows, neg_rows);
    } else {
        hipLaunchKernelGGL(mp2v_loss_f32_kernel, dim3(blocks), dim3(256), 0, stream,
                           emb, pos_rw, neg_rw, ws, pos_rows, neg_rows);
    }

    hipLaunchKernelGGL(finalize_kernel, dim3(1), dim3(1), 0, stream,
                       ws, out,
                       1.0 / (6.0 * (double)pos_rows),
                       1.0 / (6.0 * (double)neg_rows));
}

// Round 2
// 863.051 us; speedup vs baseline: 1.1740x; 1.0016x over previous
//
#include <hip/hip_runtime.h>
#include <hip/hip_fp16.h>

// MetaPath2Vec loss, round 5: VALU-thinning of the fp8 loss kernel.
//   R4 (fp8 e4m3 table, 128MB = L3-resident): loss kernel fell 317 -> ~113us
//   and left the top-5; total 1013 -> 864. Top-5 is now all harness poison
//   fills (2 x 2.048GB @ 80% HBM peak = ~632us fixed floor).
//   Arithmetic: fp16 kernel was VALUBusy 25.5% @ 317us = 81us VALU-at-100%;
//   fp8 decode adds ~1.5x VALU -> ~120us-at-100% vs ~113us measured
//   => loss kernel is now VALU-BOUND (~100% busy), memory side idle
//   (1.08GB logical / L3 would support ~65us).
//   Fix: v_pk_fma_f32 via __builtin_elementwise_fma on the f32x2 pairs that
//   v_cvt_pk_f32_fp8 already produces. Dot core: 24 -> 17 VALU per 16 elems.
//   Worst case lowers to 2 scalar fmas (== old code), no regression risk.

constexpr int DIM = 128;
constexpr int CTX = 7;

#if __has_builtin(__builtin_amdgcn_cvt_pk_fp8_f32) && __has_builtin(__builtin_amdgcn_cvt_pk_f32_fp8)
#define FP8_VIA_BUILTIN 1
#else
#define FP8_VIA_BUILTIN 0
#include <hip/hip_fp8.h>
#endif

typedef float f32x2 __attribute__((ext_vector_type(2)));

template<int IMM>
__device__ __forceinline__ int swz_i(int x) {
    return __builtin_amdgcn_ds_swizzle(x, IMM);
}
template<int IMM>
__device__ __forceinline__ float swz_f(float x) {
    return __int_as_float(__builtin_amdgcn_ds_swizzle(__float_as_int(x), IMM));
}
__device__ __forceinline__ float red8(float p) {
    p += swz_f<0x041F>(p);
    p += swz_f<0x081F>(p);
    p += swz_f<0x101F>(p);
    return p;
}

// ---------- fp8 e4m3 (OCP) encode / decode ----------
template<bool HI>
__device__ __forceinline__ unsigned enc2(float x, float y, unsigned old) {
#if FP8_VIA_BUILTIN
    return (unsigned)__builtin_amdgcn_cvt_pk_fp8_f32(x, y, (int)old, HI);
#else
    __hip_fp8_e4m3 a(x), b(y);
    unsigned w = (unsigned)a.__x | ((unsigned)b.__x << 8);
    return HI ? ((old & 0x0000ffffu) | (w << 16))
              : ((old & 0xffff0000u) | w);
#endif
}

template<bool HI>
__device__ __forceinline__ f32x2 dec2(unsigned w) {
#if FP8_VIA_BUILTIN
    return __builtin_amdgcn_cvt_pk_f32_fp8(w, HI);
#else
    unsigned lo = HI ? (w >> 16) : (w & 0xffffu);
    __hip_fp8_e4m3 a, b;
    a.__x = (unsigned char)(lo & 0xff);
    b.__x = (unsigned char)(lo >> 8);
    f32x2 r; r[0] = (float)a; r[1] = (float)b;
    return r;
#endif
}

__device__ __forceinline__ f32x2 pkfma(f32x2 a, f32x2 b, f32x2 c) {
    // lowers to v_pk_fma_f32 on gfx90a+ (2-wide f32 FMA); worst case 2x v_fma_f32
    return __builtin_elementwise_fma(a, b, c);
}

// dot of 16 fp8 elems (one uint4) against pre-decoded h pairs, packed accum.
__device__ __forceinline__ f32x2 dot16_pk(const f32x2* h2, uint4 v, f32x2 acc) {
    acc = pkfma(dec2<false>(v.x), h2[0], acc);
    acc = pkfma(dec2<true >(v.x), h2[1], acc);
    acc = pkfma(dec2<false>(v.y), h2[2], acc);
    acc = pkfma(dec2<true >(v.y), h2[3], acc);
    acc = pkfma(dec2<false>(v.z), h2[4], acc);
    acc = pkfma(dec2<true >(v.z), h2[5], acc);
    acc = pkfma(dec2<false>(v.w), h2[6], acc);
    acc = pkfma(dec2<true >(v.w), h2[7], acc);
    return acc;
}

__global__ void zero_ws_kernel(double* ws) {
    if (threadIdx.x < 2) ws[threadIdx.x] = 0.0;
}

// f32 -> fp8: read float4 (16B), write packed dword (4 fp8).
__global__ __launch_bounds__(256) void convert_fp8_kernel(
    const float4* __restrict__ in, unsigned* __restrict__ out, int n4)
{
    int i = blockIdx.x * blockDim.x + threadIdx.x;
    const int stride = gridDim.x * blockDim.x;
    for (; i < n4; i += stride) {
        float4 v = in[i];
        unsigned d = enc2<false>(v.x, v.y, 0u);
        d = enc2<true >(v.z, v.w, d);
        out[i] = d;
    }
}

// fp8 gather kernel: 8 lanes per walk-row; row = 128B = 8 uint4.
// Each lane loads ONE uint4 (16 fp8) per referenced row.
// Epilogue: lane sub keeps dot j == sub+1 (red8 broadcasts the sum),
// transcendentals run once per row instead of 6x redundantly.
__global__ __launch_bounds__(256) void mp2v_loss_fp8_kernel(
    const uint4* __restrict__ tab,
    const int*   __restrict__ pos_rw,
    const int*   __restrict__ neg_rw,
    double*      __restrict__ ws,
    int pos_rows, int neg_rows)
{
    const int tid     = blockIdx.x * blockDim.x + threadIdx.x;
    const int sub     = threadIdx.x & 7;
    const int group   = tid >> 3;
    const int ngroups = (gridDim.x * blockDim.x) >> 3;
    const int total   = pos_rows + neg_rows;

    double accPos = 0.0, accNeg = 0.0;

    int row = group;
    int nextIdx = 0;
    if (row < total) {
        const int* rw = (row < pos_rows) ? pos_rw + (size_t)row * CTX
                                         : neg_rw + (size_t)(row - pos_rows) * CTX;
        nextIdx = rw[sub < CTX ? sub : 0];
    }

    for (; row < total; row += ngroups) {
        const bool isPos = row < pos_rows;
        int myidx = nextIdx;
        // prefetch next iteration's indices (breaks idx->load serialization)
        int nrow = row + ngroups;
        if (nrow < total) {
            const int* rw = (nrow < pos_rows) ? pos_rw + (size_t)nrow * CTX
                                              : neg_rw + (size_t)(nrow - pos_rows) * CTX;
            nextIdx = rw[sub < CTX ? sub : 0];
        }

        int idx0 = swz_i<(0<<5)|0x18>(myidx);
        int idx1 = swz_i<(1<<5)|0x18>(myidx);
        int idx2 = swz_i<(2<<5)|0x18>(myidx);
        int idx3 = swz_i<(3<<5)|0x18>(myidx);
        int idx4 = swz_i<(4<<5)|0x18>(myidx);
        int idx5 = swz_i<(5<<5)|0x18>(myidx);
        int idx6 = swz_i<(6<<5)|0x18>(myidx);
        int idx[CTX] = {idx0, idx1, idx2, idx3, idx4, idx5, idx6};

        // h (start row): 8 uint4 per row; lane takes [sub]; decode to pairs once
        uint4 hv = tab[(size_t)idx[0] * 8 + sub];
        f32x2 h2[8];
        h2[0] = dec2<false>(hv.x);
        h2[1] = dec2<true >(hv.x);
        h2[2] = dec2<false>(hv.y);
        h2[3] = dec2<true >(hv.y);
        h2[4] = dec2<false>(hv.z);
        h2[5] = dec2<true >(hv.z);
        h2[6] = dec2<false>(hv.w);
        h2[7] = dec2<true >(hv.w);

        float pmine = 0.0f;
        #pragma unroll
        for (int j = 1; j < CTX; ++j) {
            uint4 cv = tab[(size_t)idx[j] * 8 + sub];
            f32x2 a = {0.0f, 0.0f};
            a = dot16_pk(h2, cv, a);
            float p = a[0] + a[1];
            p = red8(p);               // broadcasts full dot to all 8 lanes
            if (sub == j - 1) pmine = p;
        }

        // one epilogue per row; lanes 0..5 each own one of the 6 dots
        float e = __expf(-fabsf(pmine));
        float r = __frcp_rn(1.0f + e);
        float s = (pmine >= 0.0f ? 1.0f : e) * r;
        float t = isPos ? (s + 1e-15f) : (1.0f - s + 1e-15f);
        float m = (sub < CTX - 1) ? -__logf(t) : 0.0f;
        if (isPos) accPos += (double)m;
        else       accNeg += (double)m;
    }

    #pragma unroll
    for (int off = 32; off > 0; off >>= 1) {
        accPos += __shfl_down(accPos, off, 64);
        accNeg += __shfl_down(accNeg, off, 64);
    }
    __shared__ double sP[4], sN[4];
    const int wave = threadIdx.x >> 6;
    if ((threadIdx.x & 63) == 0) { sP[wave] = accPos; sN[wave] = accNeg; }
    __syncthreads();
    if (threadIdx.x == 0) {
        atomicAdd(&ws[0], sP[0] + sP[1] + sP[2] + sP[3]);
        atomicAdd(&ws[1], sN[0] + sN[1] + sN[2] + sN[3]);
    }
}

// ---------- f32 fallback (round-2 kernel), used when ws too small ----------
__global__ __launch_bounds__(256) void mp2v_loss_f32_kernel(
    const float* __restrict__ emb,
    const int*   __restrict__ pos_rw,
    const int*   __restrict__ neg_rw,
    double*      __restrict__ ws,
    int pos_rows, int neg_rows)
{
    const int tid     = blockIdx.x * blockDim.x + threadIdx.x;
    const int sub     = threadIdx.x & 7;
    const int group   = tid >> 3;
    const int ngroups = (gridDim.x * blockDim.x) >> 3;
    const int total   = pos_rows + neg_rows;

    double accPos = 0.0, accNeg = 0.0;

    for (int row = group; row < total; row += ngroups) {
        const bool isPos = row < pos_rows;
        const int* rw = isPos ? pos_rw + (size_t)row * CTX
                              : neg_rw + (size_t)(row - pos_rows) * CTX;
        int myidx = rw[sub < CTX ? sub : 0];

        int idx0 = swz_i<(0<<5)|0x18>(myidx);
        int idx1 = swz_i<(1<<5)|0x18>(myidx);
        int idx2 = swz_i<(2<<5)|0x18>(myidx);
        int idx3 = swz_i<(3<<5)|0x18>(myidx);
        int idx4 = swz_i<(4<<5)|0x18>(myidx);
        int idx5 = swz_i<(5<<5)|0x18>(myidx);
        int idx6 = swz_i<(6<<5)|0x18>(myidx);
        int idx[CTX] = {idx0, idx1, idx2, idx3, idx4, idx5, idx6};

        const float* h0p = emb + (size_t)idx[0] * DIM + sub * 4;
        float4 ha = *(const float4*)(h0p);
        float4 hb = *(const float4*)(h0p + 32);
        float4 hc = *(const float4*)(h0p + 64);
        float4 hd = *(const float4*)(h0p + 96);

        float rowLoss = 0.0f;
        #pragma unroll
        for (int j = 1; j < CTX; ++j) {
            const float* cp = emb + (size_t)idx[j] * DIM + sub * 4;
            float4 ca = *(const float4*)(cp);
            float4 cb = *(const float4*)(cp + 32);
            float4 cc = *(const float4*)(cp + 64);
            float4 cd = *(const float4*)(cp + 96);
            float p = ha.x*ca.x + ha.y*ca.y + ha.z*ca.z + ha.w*ca.w;
            p = fmaf(hb.x, cb.x, fmaf(hb.y, cb.y, fmaf(hb.z, cb.z, fmaf(hb.w, cb.w, p))));
            p = fmaf(hc.x, cc.x, fmaf(hc.y, cc.y, fmaf(hc.z, cc.z, fmaf(hc.w, cc.w, p))));
            p = fmaf(hd.x, cd.x, fmaf(hd.y, cd.y, fmaf(hd.z, cd.z, fmaf(hd.w, cd.w, p))));
            p = red8(p);

            float e = __expf(-fabsf(p));
            float r = __frcp_rn(1.0f + e);
            float s = (p >= 0.0f ? 1.0f : e) * r;
            float t = isPos ? (s + 1e-15f) : (1.0f - s + 1e-15f);
            rowLoss -= __logf(t);
        }
        float m = (sub == 0) ? rowLoss : 0.0f;
        if (isPos) accPos += (double)m;
        else       accNeg += (double)m;
    }

    #pragma unroll
    for (int off = 32; off > 0; off >>= 1) {
        accPos += __shfl_down(accPos, off, 64);
        accNeg += __shfl_down(accNeg, off, 64);
    }
    __shared__ double sP[4], sN[4];
    const int wave = threadIdx.x >> 6;
    if ((threadIdx.x & 63) == 0) { sP[wave] = accPos; sN[wave] = accNeg; }
    __syncthreads();
    if (threadIdx.x == 0) {
        atomicAdd(&ws[0], sP[0] + sP[1] + sP[2] + sP[3]);
        atomicAdd(&ws[1], sN[0] + sN[1] + sN[2] + sN[3]);
    }
}

__global__ void finalize_kernel(const double* __restrict__ ws,
                                float* __restrict__ out,
                                double invPosCnt, double invNegCnt)
{
    out[0] = (float)(ws[0] * invPosCnt + ws[1] * invNegCnt);
}

extern "C" void kernel_launch(void* const* d_in, const int* in_sizes, int n_in,
                              void* d_out, int out_size, void* d_ws, size_t ws_size,
                              hipStream_t stream)
{
    const float* emb    = (const float*)d_in[0];
    const int*   pos_rw = (const int*)d_in[1];
    const int*   neg_rw = (const int*)d_in[2];
    float*       out    = (float*)d_out;
    double*      ws     = (double*)d_ws;

    const int pos_rows = in_sizes[1] / CTX;   // 200000
    const int neg_rows = in_sizes[2] / CTX;   // 1000000
    const int n_emb_elems = in_sizes[0];      // 128,000,128

    const size_t table_bytes = (size_t)n_emb_elems;       // fp8 table, 1B/elem
    const size_t need = 256 + table_bytes;

    hipLaunchKernelGGL(zero_ws_kernel, dim3(1), dim3(64), 0, stream, ws);

    const int blocks = 4096;
    if (ws_size >= need) {
        unsigned* tab_w = (unsigned*)((char*)d_ws + 256);
        hipLaunchKernelGGL(convert_fp8_kernel, dim3(4096), dim3(256), 0, stream,
                           (const float4*)emb, tab_w, n_emb_elems / 4);
        hipLaunchKernelGGL(mp2v_loss_fp8_kernel, dim3(blocks), dim3(256), 0, stream,
                           (const uint4*)((char*)d_ws + 256), pos_rw, neg_rw, ws,
                           pos_rows, neg_rows);
    } else {
        hipLaunchKernelGGL(mp2v_loss_f32_kernel, dim3(blocks), dim3(256), 0, stream,
                           emb, pos_rw, neg_rw, ws, pos_rows, neg_rows);
    }

    hipLaunchKernelGGL(finalize_kernel, dim3(1), dim3(1), 0, stream,
                       ws, out,
                       1.0 / (6.0 * (double)pos_rows),
                       1.0 / (6.0 * (double)neg_rows));
}

// Round 3
// 850.341 us; speedup vs baseline: 1.1915x; 1.0149x over previous
//
#include <hip/hip_runtime.h>
#include <hip/hip_fp16.h>

// MetaPath2Vec loss, round 6: MLP-doubling of the fp8 loss kernel.
//   R5 post-mortem: pk_fma (-30% dot VALU) was NEUTRAL -> loss kernel is NOT
//   VALU-bound. Static count: ~25us VALU-at-100% vs ~113us duration => the
//   kernel is gather-bound. Either L3 random-gather service (1.075GB/113us =
//   9.5 TB/s) or latency-bound (only 7x16B in flight per lane, VGPR=36,
//   8 waves/SIMD HW cap).
//   Decisive experiment: unroll walk loop x2 -> 14 gathers issued up-front
//   per group-iteration. h re-decoded per dot (VALU is idle; saves 12 VGPR,
//   targets ~75 VGPR / 6 waves/SIMD -> >=1.5x bytes in flight).
//   Also: ws zeroing folded into convert kernel (one less launch).
//   If neutral: loss is at the L3 service ceiling -> roofline next round.

constexpr int DIM = 128;
constexpr int CTX = 7;

#if __has_builtin(__builtin_amdgcn_cvt_pk_fp8_f32) && __has_builtin(__builtin_amdgcn_cvt_pk_f32_fp8)
#define FP8_VIA_BUILTIN 1
#else
#define FP8_VIA_BUILTIN 0
#include <hip/hip_fp8.h>
#endif

typedef float f32x2 __attribute__((ext_vector_type(2)));

template<int IMM>
__device__ __forceinline__ int swz_i(int x) {
    return __builtin_amdgcn_ds_swizzle(x, IMM);
}
template<int IMM>
__device__ __forceinline__ float swz_f(float x) {
    return __int_as_float(__builtin_amdgcn_ds_swizzle(__float_as_int(x), IMM));
}
__device__ __forceinline__ float red8(float p) {
    p += swz_f<0x041F>(p);
    p += swz_f<0x081F>(p);
    p += swz_f<0x101F>(p);
    return p;
}

// ---------- fp8 e4m3 (OCP) encode / decode ----------
template<bool HI>
__device__ __forceinline__ unsigned enc2(float x, float y, unsigned old) {
#if FP8_VIA_BUILTIN
    return (unsigned)__builtin_amdgcn_cvt_pk_fp8_f32(x, y, (int)old, HI);
#else
    __hip_fp8_e4m3 a(x), b(y);
    unsigned w = (unsigned)a.__x | ((unsigned)b.__x << 8);
    return HI ? ((old & 0x0000ffffu) | (w << 16))
              : ((old & 0xffff0000u) | w);
#endif
}

template<bool HI>
__device__ __forceinline__ f32x2 dec2(unsigned w) {
#if FP8_VIA_BUILTIN
    return __builtin_amdgcn_cvt_pk_f32_fp8(w, HI);
#else
    unsigned lo = HI ? (w >> 16) : (w & 0xffffu);
    __hip_fp8_e4m3 a, b;
    a.__x = (unsigned char)(lo & 0xff);
    b.__x = (unsigned char)(lo >> 8);
    f32x2 r; r[0] = (float)a; r[1] = (float)b;
    return r;
#endif
}

__device__ __forceinline__ f32x2 pkfma(f32x2 a, f32x2 b, f32x2 c) {
    // lowers to v_pk_fma_f32 on gfx90a+ (2-wide f32 FMA)
    return __builtin_elementwise_fma(a, b, c);
}

// dot of 16 fp8 elems: h and c both decoded inline (h kept packed to save VGPRs)
__device__ __forceinline__ float dot16_hc(uint4 h, uint4 c) {
    f32x2 a = {0.0f, 0.0f};
    a = pkfma(dec2<false>(h.x), dec2<false>(c.x), a);
    a = pkfma(dec2<true >(h.x), dec2<true >(c.x), a);
    a = pkfma(dec2<false>(h.y), dec2<false>(c.y), a);
    a = pkfma(dec2<true >(h.y), dec2<true >(c.y), a);
    a = pkfma(dec2<false>(h.z), dec2<false>(c.z), a);
    a = pkfma(dec2<true >(h.z), dec2<true >(c.z), a);
    a = pkfma(dec2<false>(h.w), dec2<false>(c.w), a);
    a = pkfma(dec2<true >(h.w), dec2<true >(c.w), a);
    return a[0] + a[1];
}

__global__ void zero_ws_kernel(double* ws) {
    if (threadIdx.x < 2) ws[threadIdx.x] = 0.0;
}

// f32 -> fp8: read float4 (16B), write packed dword (4 fp8).
// Also zeroes the two accumulator doubles (saves a launch; loss runs after).
__global__ __launch_bounds__(256) void convert_fp8_kernel(
    const float4* __restrict__ in, unsigned* __restrict__ out, int n4,
    double* __restrict__ ws)
{
    if (blockIdx.x == 0 && threadIdx.x < 2) ws[threadIdx.x] = 0.0;
    int i = blockIdx.x * blockDim.x + threadIdx.x;
    const int stride = gridDim.x * blockDim.x;
    for (; i < n4; i += stride) {
        float4 v = in[i];
        unsigned d = enc2<false>(v.x, v.y, 0u);
        d = enc2<true >(v.z, v.w, d);
        out[i] = d;
    }
}

// fp8 gather kernel, unroll-2: 8 lanes per walk-row; row = 128B = 8 uint4.
// Each group processes TWO walks per iteration; all 14 row-gathers are
// issued before any dot consumes them (2x memory-level parallelism).
__global__ __launch_bounds__(256) void mp2v_loss_fp8_kernel(
    const uint4* __restrict__ tab,
    const int*   __restrict__ pos_rw,
    const int*   __restrict__ neg_rw,
    double*      __restrict__ ws,
    int pos_rows, int neg_rows)
{
    const int tid     = blockIdx.x * blockDim.x + threadIdx.x;
    const int sub     = threadIdx.x & 7;
    const int group   = tid >> 3;
    const int ngroups = (gridDim.x * blockDim.x) >> 3;
    const int total   = pos_rows + neg_rows;
    const int stride  = ngroups * 2;

    double accPos = 0.0, accNeg = 0.0;

    // index fetch for row r (clamped; lane sub reads rw[sub], lane 7 reads rw[0])
    auto idx_of = [&](int r) -> int {
        int rc = r < total ? r : total - 1;
        const int* rw = (rc < pos_rows) ? pos_rw + (size_t)rc * CTX
                                        : neg_rw + (size_t)(rc - pos_rows) * CTX;
        return rw[sub < CTX ? sub : 0];
    };

    int nextA = 0, nextB = 0;
    if (group < total) {
        nextA = idx_of(group);
        nextB = idx_of(group + ngroups);
    }

    for (int row = group; row < total; row += stride) {
        const int  rB     = row + ngroups;
        const bool validB = rB < total;
        const bool isPosA = row < pos_rows;
        const bool isPosB = rB < pos_rows;   // false when invalid (rB >= total)

        const int myA = nextA, myB = nextB;
        // prefetch next pair's indices (breaks idx->load serialization)
        nextA = idx_of(row + stride);
        nextB = idx_of(rB + stride);

        // broadcast each lane's index to the whole 8-lane group
        const int iA0 = swz_i<(0<<5)|0x18>(myA), iA1 = swz_i<(1<<5)|0x18>(myA),
                  iA2 = swz_i<(2<<5)|0x18>(myA), iA3 = swz_i<(3<<5)|0x18>(myA),
                  iA4 = swz_i<(4<<5)|0x18>(myA), iA5 = swz_i<(5<<5)|0x18>(myA),
                  iA6 = swz_i<(6<<5)|0x18>(myA);
        const int iB0 = swz_i<(0<<5)|0x18>(myB), iB1 = swz_i<(1<<5)|0x18>(myB),
                  iB2 = swz_i<(2<<5)|0x18>(myB), iB3 = swz_i<(3<<5)|0x18>(myB),
                  iB4 = swz_i<(4<<5)|0x18>(myB), iB5 = swz_i<(5<<5)|0x18>(myB),
                  iB6 = swz_i<(6<<5)|0x18>(myB);

        // issue ALL 14 gathers up-front
        const uint4 hA  = tab[(size_t)iA0 * 8 + sub];
        const uint4 cA1 = tab[(size_t)iA1 * 8 + sub];
        const uint4 cA2 = tab[(size_t)iA2 * 8 + sub];
        const uint4 cA3 = tab[(size_t)iA3 * 8 + sub];
        const uint4 cA4 = tab[(size_t)iA4 * 8 + sub];
        const uint4 cA5 = tab[(size_t)iA5 * 8 + sub];
        const uint4 cA6 = tab[(size_t)iA6 * 8 + sub];
        const uint4 hB  = tab[(size_t)iB0 * 8 + sub];
        const uint4 cB1 = tab[(size_t)iB1 * 8 + sub];
        const uint4 cB2 = tab[(size_t)iB2 * 8 + sub];
        const uint4 cB3 = tab[(size_t)iB3 * 8 + sub];
        const uint4 cB4 = tab[(size_t)iB4 * 8 + sub];
        const uint4 cB5 = tab[(size_t)iB5 * 8 + sub];
        const uint4 cB6 = tab[(size_t)iB6 * 8 + sub];

        // walk A: 6 dots; red8 broadcasts each dot's total; lane j-1 keeps dot j
        float pA = 0.0f, pB = 0.0f;
        { float p = red8(dot16_hc(hA, cA1)); if (sub == 0) pA = p; }
        { float p = red8(dot16_hc(hA, cA2)); if (sub == 1) pA = p; }
        { float p = red8(dot16_hc(hA, cA3)); if (sub == 2) pA = p; }
        { float p = red8(dot16_hc(hA, cA4)); if (sub == 3) pA = p; }
        { float p = red8(dot16_hc(hA, cA5)); if (sub == 4) pA = p; }
        { float p = red8(dot16_hc(hA, cA6)); if (sub == 5) pA = p; }
        // walk B
        { float p = red8(dot16_hc(hB, cB1)); if (sub == 0) pB = p; }
        { float p = red8(dot16_hc(hB, cB2)); if (sub == 1) pB = p; }
        { float p = red8(dot16_hc(hB, cB3)); if (sub == 2) pB = p; }
        { float p = red8(dot16_hc(hB, cB4)); if (sub == 3) pB = p; }
        { float p = red8(dot16_hc(hB, cB5)); if (sub == 4) pB = p; }
        { float p = red8(dot16_hc(hB, cB6)); if (sub == 5) pB = p; }

        // epilogues: lanes 0..5 each own one dot; one transcendental pass per walk
        float eA = __expf(-fabsf(pA));
        float rA = __frcp_rn(1.0f + eA);
        float sA = (pA >= 0.0f ? 1.0f : eA) * rA;
        float tA = isPosA ? (sA + 1e-15f) : (1.0f - sA + 1e-15f);
        float mA = (sub < CTX - 1) ? -__logf(tA) : 0.0f;

        float eB = __expf(-fabsf(pB));
        float rB2 = __frcp_rn(1.0f + eB);
        float sB = (pB >= 0.0f ? 1.0f : eB) * rB2;
        float tB = isPosB ? (sB + 1e-15f) : (1.0f - sB + 1e-15f);
        float mB = (validB && sub < CTX - 1) ? -__logf(tB) : 0.0f;

        if (isPosA) accPos += (double)mA; else accNeg += (double)mA;
        if (isPosB) accPos += (double)mB; else accNeg += (double)mB;
    }

    #pragma unroll
    for (int off = 32; off > 0; off >>= 1) {
        accPos += __shfl_down(accPos, off, 64);
        accNeg += __shfl_down(accNeg, off, 64);
    }
    __shared__ double sP[4], sN[4];
    const int wave = threadIdx.x >> 6;
    if ((threadIdx.x & 63) == 0) { sP[wave] = accPos; sN[wave] = accNeg; }
    __syncthreads();
    if (threadIdx.x == 0) {
        atomicAdd(&ws[0], sP[0] + sP[1] + sP[2] + sP[3]);
        atomicAdd(&ws[1], sN[0] + sN[1] + sN[2] + sN[3]);
    }
}

// ---------- f32 fallback (round-2 kernel), used when ws too small ----------
__global__ __launch_bounds__(256) void mp2v_loss_f32_kernel(
    const float* __restrict__ emb,
    const int*   __restrict__ pos_rw,
    const int*   __restrict__ neg_rw,
    double*      __restrict__ ws,
    int pos_rows, int neg_rows)
{
    const int tid     = blockIdx.x * blockDim.x + threadIdx.x;
    const int sub     = threadIdx.x & 7;
    const int group   = tid >> 3;
    const int ngroups = (gridDim.x * blockDim.x) >> 3;
    const int total   = pos_rows + neg_rows;

    double accPos = 0.0, accNeg = 0.0;

    for (int row = group; row < total; row += ngroups) {
        const bool isPos = row < pos_rows;
        const int* rw = isPos ? pos_rw + (size_t)row * CTX
                              : neg_rw + (size_t)(row - pos_rows) * CTX;
        int myidx = rw[sub < CTX ? sub : 0];

        int idx0 = swz_i<(0<<5)|0x18>(myidx);
        int idx1 = swz_i<(1<<5)|0x18>(myidx);
        int idx2 = swz_i<(2<<5)|0x18>(myidx);
        int idx3 = swz_i<(3<<5)|0x18>(myidx);
        int idx4 = swz_i<(4<<5)|0x18>(myidx);
        int idx5 = swz_i<(5<<5)|0x18>(myidx);
        int idx6 = swz_i<(6<<5)|0x18>(myidx);
        int idx[CTX] = {idx0, idx1, idx2, idx3, idx4, idx5, idx6};

        const float* h0p = emb + (size_t)idx[0] * DIM + sub * 4;
        float4 ha = *(const float4*)(h0p);
        float4 hb = *(const float4*)(h0p + 32);
        float4 hc = *(const float4*)(h0p + 64);
        float4 hd = *(const float4*)(h0p + 96);

        float rowLoss = 0.0f;
        #pragma unroll
        for (int j = 1; j < CTX; ++j) {
            const float* cp = emb + (size_t)idx[j] * DIM + sub * 4;
            float4 ca = *(const float4*)(cp);
            float4 cb = *(const float4*)(cp + 32);
            float4 cc = *(const float4*)(cp + 64);
            float4 cd = *(const float4*)(cp + 96);
            float p = ha.x*ca.x + ha.y*ca.y + ha.z*ca.z + ha.w*ca.w;
            p = fmaf(hb.x, cb.x, fmaf(hb.y, cb.y, fmaf(hb.z, cb.z, fmaf(hb.w, cb.w, p))));
            p = fmaf(hc.x, cc.x, fmaf(hc.y, cc.y, fmaf(hc.z, cc.z, fmaf(hc.w, cc.w, p))));
            p = fmaf(hd.x, cd.x, fmaf(hd.y, cd.y, fmaf(hd.z, cd.z, fmaf(hd.w, cd.w, p))));
            p = red8(p);

            float e = __expf(-fabsf(p));
            float r = __frcp_rn(1.0f + e);
            float s = (p >= 0.0f ? 1.0f : e) * r;
            float t = isPos ? (s + 1e-15f) : (1.0f - s + 1e-15f);
            rowLoss -= __logf(t);
        }
        float m = (sub == 0) ? rowLoss : 0.0f;
        if (isPos) accPos += (double)m;
        else       accNeg += (double)m;
    }

    #pragma unroll
    for (int off = 32; off > 0; off >>= 1) {
        accPos += __shfl_down(accPos, off, 64);
        accNeg += __shfl_down(accNeg, off, 64);
    }
    __shared__ double sP[4], sN[4];
    const int wave = threadIdx.x >> 6;
    if ((threadIdx.x & 63) == 0) { sP[wave] = accPos; sN[wave] = accNeg; }
    __syncthreads();
    if (threadIdx.x == 0) {
        atomicAdd(&ws[0], sP[0] + sP[1] + sP[2] + sP[3]);
        atomicAdd(&ws[1], sN[0] + sN[1] + sN[2] + sN[3]);
    }
}

__global__ void finalize_kernel(const double* __restrict__ ws,
                                float* __restrict__ out,
                                double invPosCnt, double invNegCnt)
{
    out[0] = (float)(ws[0] * invPosCnt + ws[1] * invNegCnt);
}

extern "C" void kernel_launch(void* const* d_in, const int* in_sizes, int n_in,
                              void* d_out, int out_size, void* d_ws, size_t ws_size,
                              hipStream_t stream)
{
    const float* emb    = (const float*)d_in[0];
    const int*   pos_rw = (const int*)d_in[1];
    const int*   neg_rw = (const int*)d_in[2];
    float*       out    = (float*)d_out;
    double*      ws     = (double*)d_ws;

    const int pos_rows = in_sizes[1] / CTX;   // 200000
    const int neg_rows = in_sizes[2] / CTX;   // 1000000
    const int n_emb_elems = in_sizes[0];      // 128,000,128

    const size_t table_bytes = (size_t)n_emb_elems;       // fp8 table, 1B/elem
    const size_t need = 256 + table_bytes;

    const int blocks = 4096;
    if (ws_size >= need) {
        unsigned* tab_w = (unsigned*)((char*)d_ws + 256);
        hipLaunchKernelGGL(convert_fp8_kernel, dim3(4096), dim3(256), 0, stream,
                           (const float4*)emb, tab_w, n_emb_elems / 4, ws);
        hipLaunchKernelGGL(mp2v_loss_fp8_kernel, dim3(blocks), dim3(256), 0, stream,
                           (const uint4*)((char*)d_ws + 256), pos_rw, neg_rw, ws,
                           pos_rows, neg_rows);
    } else {
        hipLaunchKernelGGL(zero_ws_kernel, dim3(1), dim3(64), 0, stream, ws);
        hipLaunchKernelGGL(mp2v_loss_f32_kernel, dim3(blocks), dim3(256), 0, stream,
                           emb, pos_rw, neg_rw, ws, pos_rows, neg_rows);
    }

    hipLaunchKernelGGL(finalize_kernel, dim3(1), dim3(1), 0, stream,
                       ws, out,
                       1.0 / (6.0 * (double)pos_rows),
                       1.0 / (6.0 * (double)neg_rows));
}